// Round 1
// baseline (938.043 us; speedup 1.0000x reference)
//
#include <hip/hip_runtime.h>
#include <hip/hip_bf16.h>
#include <stdint.h>

#define SQ 2048
#define SKV 2048
#define DM 2048
#define NH 32
#define DH 64

using s16x8 = __attribute__((ext_vector_type(8))) short;   // 8 bf16 (4 VGPRs)
using f32x4 = __attribute__((ext_vector_type(4))) float;   // MFMA C/D

// round-to-nearest-even f32 -> bf16 bits
__device__ __forceinline__ unsigned short f2bf(float x) {
  union { float f; uint32_t u; } v; v.f = x;
  uint32_t r = (v.u + 0x7fffu + ((v.u >> 16) & 1u)) >> 16;
  return (unsigned short)r;
}

__device__ __forceinline__ void gl_lds16(const void* g, void* l) {
  __builtin_amdgcn_global_load_lds(
      (const __attribute__((address_space(1))) uint32_t*)g,
      (__attribute__((address_space(3))) uint32_t*)l, 16, 0, 0);
}

// ---------------- prep: f32 -> bf16 for 6 tensors (each 2^22 elems) ----------------
__global__ __launch_bounds__(256) void prep_cvt(
    const float* __restrict__ hq, const float* __restrict__ hkv,
    const float* __restrict__ wq, const float* __restrict__ wk,
    const float* __restrict__ wv, const float* __restrict__ wo,
    unsigned short* __restrict__ out) {
  const int total = 6 << 20;  // 6 tensors x 2^20 float4
  for (int idx = blockIdx.x * blockDim.x + threadIdx.x; idx < total;
       idx += gridDim.x * blockDim.x) {
    int seg = idx >> 20;
    int off = (idx & ((1 << 20) - 1)) << 2;  // element offset
    const float* src;
    switch (seg) {
      case 0: src = hq; break;
      case 1: src = hkv; break;
      case 2: src = wq; break;
      case 3: src = wk; break;
      case 4: src = wv; break;
      default: src = wo; break;
    }
    float4 v = *(const float4*)(src + off);
    ushort4 o;
    o.x = f2bf(v.x); o.y = f2bf(v.y); o.z = f2bf(v.z); o.w = f2bf(v.w);
    *(ushort4*)(out + (((size_t)seg) << 22) + off) = o;
  }
}

// ---------------- prep: pack mask (int32 0/1) into bitmask ----------------
__global__ __launch_bounds__(256) void prep_mask(const int* __restrict__ mask,
                                                 uint32_t* __restrict__ bits) {
  int i = blockIdx.x * blockDim.x + threadIdx.x;  // < SQ*SKV
  int m = mask[i];
  unsigned long long b = __ballot(m != 0);
  int lane = threadIdx.x & 63;
  if (lane == 0) bits[i >> 5] = (uint32_t)b;
  else if (lane == 32) bits[i >> 5] = (uint32_t)(b >> 32);
}

// ---------------- shared GEMM core: C[M=2048][N=2048] = A @ W^T + bias ----------------
// A, W row-major bf16 with K=2048. 128x128 tile, BK=32, 4 waves, 2-phase dbuf LDS.
// mode 0: out_bf16[h][row][d] (per-head, h=col>>6)     (Q, K)
// mode 1: out_bf16[col][row]  (transposed: V^T [h*64+d][skv])
// mode 2: out_f32[row][col]                            (final projection)
__device__ __forceinline__ void gemm_core(const unsigned short* __restrict__ A,
                                          const unsigned short* __restrict__ W,
                                          const float* __restrict__ bias,
                                          unsigned short* __restrict__ outb,
                                          float* __restrict__ outf, int mode) {
  __shared__ __align__(16) char lds[32768];  // 2 x (A 8KB + B 8KB)
  const int tid = threadIdx.x;
  const int lane = tid & 63;
  const int w = tid >> 6;
  const int bm0 = blockIdx.y * 128, bn0 = blockIdx.x * 128;
  const int wr = w >> 1, wc = w & 1;  // wave -> 64x64 subtile
  const char* Ab = (const char*)A;
  const char* Wb = (const char*)W;

  f32x4 acc[4][4] = {};

  auto stage = [&](int buf, int k0) {
#pragma unroll
    for (int c = 0; c < 2; ++c) {
      int L = c * 4096 + tid * 16;
      int row = L >> 6, koff = L & 63;
      gl_lds16(Ab + (size_t)(bm0 + row) * 4096 + k0 * 2 + koff,
               lds + buf * 16384 + L);
    }
#pragma unroll
    for (int c = 0; c < 2; ++c) {
      int L = c * 4096 + tid * 16;
      int row = L >> 6, koff = L & 63;
      gl_lds16(Wb + (size_t)(bn0 + row) * 4096 + k0 * 2 + koff,
               lds + buf * 16384 + 8192 + L);
    }
  };

  stage(0, 0);
  __syncthreads();
  const int NT = 2048 / 32;
  const int g16 = (lane >> 4) * 16;
  for (int t = 0; t < NT; ++t) {
    int buf = t & 1;
    if (t + 1 < NT) stage(buf ^ 1, (t + 1) * 32);
    const char* Al = lds + buf * 16384;
    const char* Bl = Al + 8192;
    s16x8 af[4], bfr[4];
#pragma unroll
    for (int m = 0; m < 4; ++m)
      af[m] = *(const s16x8*)(Al + (wr * 64 + m * 16 + (lane & 15)) * 64 + g16);
#pragma unroll
    for (int n = 0; n < 4; ++n)
      bfr[n] = *(const s16x8*)(Bl + (wc * 64 + n * 16 + (lane & 15)) * 64 + g16);
#pragma unroll
    for (int m = 0; m < 4; ++m)
#pragma unroll
      for (int n = 0; n < 4; ++n)
        acc[m][n] = __builtin_amdgcn_mfma_f32_16x16x32_bf16(af[m], bfr[n],
                                                            acc[m][n], 0, 0, 0);
    __syncthreads();
  }
  // epilogue; D layout: col = lane&15, row = (lane>>4)*4 + r
#pragma unroll
  for (int n = 0; n < 4; ++n) {
    int gcol = bn0 + wc * 64 + n * 16 + (lane & 15);
    float bv_ = bias[gcol];
#pragma unroll
    for (int m = 0; m < 4; ++m) {
#pragma unroll
      for (int r = 0; r < 4; ++r) {
        int grow = bm0 + wr * 64 + m * 16 + (lane >> 4) * 4 + r;
        float v = acc[m][n][r] + bv_;
        if (mode == 0) {
          int h = gcol >> 6, d = gcol & 63;
          outb[((size_t)h * SQ + grow) * 64 + d] = f2bf(v);
        } else if (mode == 1) {
          outb[(size_t)gcol * SKV + grow] = f2bf(v);
        } else {
          outf[(size_t)grow * DM + gcol] = v;
        }
      }
    }
  }
}

__global__ __launch_bounds__(256) void qkv_gemm(
    const unsigned short* __restrict__ cvt,  // [hqb, hkvb, wqb, wkb, wvb, wob]
    const float* __restrict__ bq, const float* __restrict__ bk,
    const float* __restrict__ bv, unsigned short* __restrict__ Qh,
    unsigned short* __restrict__ Kh, unsigned short* __restrict__ VhT) {
  int z = blockIdx.z;
  const unsigned short* A = cvt + ((z == 0) ? 0 : ((size_t)1 << 22));
  const unsigned short* W = cvt + ((size_t)(2 + z) << 22);
  const float* bias = (z == 0) ? bq : (z == 1) ? bk : bv;
  unsigned short* out = (z == 0) ? Qh : (z == 1) ? Kh : VhT;
  gemm_core(A, W, bias, out, nullptr, (z == 2) ? 1 : 0);
}

__global__ __launch_bounds__(256) void out_gemm(
    const unsigned short* __restrict__ aout, const unsigned short* __restrict__ wob,
    const float* __restrict__ bo, float* __restrict__ out) {
  gemm_core(aout, wob, bo, nullptr, out, 2);
}

// ---------------- flash attention ----------------
// grid (SQ/128, NH), 256 threads (4 waves x 32 q-rows). BN=64 kv per tile.
__global__ __launch_bounds__(256) void attn(
    const unsigned short* __restrict__ Qh, const unsigned short* __restrict__ Kh,
    const unsigned short* __restrict__ VhT, const uint32_t* __restrict__ mbits,
    const float* __restrict__ pbias, unsigned short* __restrict__ aout) {
  __shared__ __align__(16) char lds[16384 + 8192 + 64 * 144 + 4 * 32 * 144];
  char* Qt = lds;                    // [128][128B], XOR-swizzled rows
  char* Kt = lds + 16384;            // [64][128B], XOR-swizzled rows
  char* Vt = Kt + 8192;              // V^T [64 d][144B padded] (64 kv cols)
  char* Pt = Vt + 64 * 144;          // per-wave P [32][144B padded]

  const int tid = threadIdx.x, lane = tid & 63, w = tid >> 6;
  const int col16 = lane & 15;
  const int g4 = (lane >> 4) * 4;
  const int q0 = blockIdx.x * 128;
  const int h = blockIdx.y;

  const char* Qg = (const char*)Qh + ((size_t)h * SQ + q0) * 128;
  const char* Kg = (const char*)Kh + (size_t)h * SKV * 128;
  const char* Vg = (const char*)VhT + (size_t)h * 64 * SKV * 2;
  char* Pw = Pt + w * (32 * 144);

  // stage Q tile (16KB, 4 chunks), source pre-swizzled so reads are conflict-light
#pragma unroll
  for (int c = 0; c < 4; ++c) {
    int L = c * 4096 + tid * 16;
    int row = L >> 7, off = L & 127;
    gl_lds16(Qg + row * 128 + (off ^ ((row & 7) << 4)), Qt + L);
  }
  __syncthreads();

  // Q fragments in registers for the whole kernel
  s16x8 qf[2][2];
#pragma unroll
  for (int m = 0; m < 2; ++m)
#pragma unroll
    for (int kg = 0; kg < 2; ++kg) {
      int row = w * 32 + m * 16 + col16;
      int off = kg * 64 + (lane >> 4) * 16;
      qf[m][kg] = *(const s16x8*)(Qt + row * 128 + (off ^ ((row & 7) << 4)));
    }

  f32x4 Oacc[2][4] = {};
  float mrow[2][4], lrow[2][4];
#pragma unroll
  for (int m = 0; m < 2; ++m)
#pragma unroll
    for (int r = 0; r < 4; ++r) { mrow[m][r] = -1e30f; lrow[m][r] = 0.f; }

  for (int kv0 = 0; kv0 < SKV; kv0 += 64) {
    // stage K tile [64][128B] swizzled
#pragma unroll
    for (int c = 0; c < 2; ++c) {
      int L = c * 4096 + tid * 16;
      int row = L >> 7, off = L & 127;
      gl_lds16(Kg + (size_t)(kv0 + row) * 128 + (off ^ ((row & 7) << 4)), Kt + L);
    }
    // stage V^T tile [64][64 kv] -> padded LDS rows (reg-staged: pad breaks gl_lds)
#pragma unroll
    for (int c = 0; c < 2; ++c) {
      int idx = c * 256 + tid;  // 512 chunks of 16B
      int d = idx >> 3, koff = (idx & 7) * 16;
      s16x8 v = *(const s16x8*)(Vg + (size_t)d * (SKV * 2) + kv0 * 2 + koff);
      *(s16x8*)(Vt + d * 144 + koff) = v;
    }
    __syncthreads();

    // S = Q K^T
    f32x4 sacc[2][4] = {};
    s16x8 kf[4][2];
#pragma unroll
    for (int n = 0; n < 4; ++n)
#pragma unroll
      for (int kg = 0; kg < 2; ++kg) {
        int row = n * 16 + col16;
        int off = kg * 64 + (lane >> 4) * 16;
        kf[n][kg] = *(const s16x8*)(Kt + row * 128 + (off ^ ((row & 7) << 4)));
      }
#pragma unroll
    for (int m = 0; m < 2; ++m)
#pragma unroll
      for (int n = 0; n < 4; ++n)
#pragma unroll
        for (int kg = 0; kg < 2; ++kg)
          sacc[m][n] = __builtin_amdgcn_mfma_f32_16x16x32_bf16(
              qf[m][kg], kf[n][kg], sacc[m][n], 0, 0, 0);

    // scale + bias + mask (bias streamed straight from HBM — used once)
#pragma unroll
    for (int m = 0; m < 2; ++m) {
#pragma unroll
      for (int r = 0; r < 4; ++r) {
        int grow = q0 + w * 32 + m * 16 + g4 + r;
        uint32_t w0 = mbits[(size_t)grow * 64 + (kv0 >> 5)];
        uint32_t w1 = mbits[(size_t)grow * 64 + (kv0 >> 5) + 1];
#pragma unroll
        for (int n = 0; n < 4; ++n) {
          int kcol = n * 16 + col16;
          float bval = pbias[((size_t)h * SQ + grow) * SKV + kv0 + kcol];
          float sv = fmaf(sacc[m][n][r], 0.125f, bval);
          uint32_t word = (kcol < 32) ? w0 : w1;
          if (!((word >> (kcol & 31)) & 1u)) sv = -1e30f;
          sacc[m][n][r] = sv;
        }
      }
    }

    // online softmax (wave-parallel: register max over n, shfl_xor over 16 lanes)
#pragma unroll
    for (int m = 0; m < 2; ++m) {
#pragma unroll
      for (int r = 0; r < 4; ++r) {
        float mx = fmaxf(fmaxf(sacc[m][0][r], sacc[m][1][r]),
                         fmaxf(sacc[m][2][r], sacc[m][3][r]));
#pragma unroll
        for (int sh = 1; sh < 16; sh <<= 1) mx = fmaxf(mx, __shfl_xor(mx, sh));
        float mnew = fmaxf(mrow[m][r], mx);
        float scale = __expf(mrow[m][r] - mnew);
        mrow[m][r] = mnew;
        float rsum = 0.f;
#pragma unroll
        for (int n = 0; n < 4; ++n) {
          float p = __expf(sacc[m][n][r] - mnew);
          sacc[m][n][r] = p;
          rsum += p;
        }
#pragma unroll
        for (int sh = 1; sh < 16; sh <<= 1) rsum += __shfl_xor(rsum, sh);
        lrow[m][r] = lrow[m][r] * scale + rsum;
#pragma unroll
        for (int df = 0; df < 4; ++df) Oacc[m][df][r] *= scale;
        int prow = m * 16 + g4 + r;
#pragma unroll
        for (int n = 0; n < 4; ++n)
          *(unsigned short*)(Pw + prow * 144 + (n * 16 + col16) * 2) =
              f2bf(sacc[m][n][r]);
      }
    }
    // make this wave's P writes visible to its own ds_reads
    asm volatile("s_waitcnt lgkmcnt(0)" ::: "memory");
    __builtin_amdgcn_sched_barrier(0);

    // O += P V   (A = P from per-wave LDS, B = V^T rows: contiguous b128)
#pragma unroll
    for (int ks = 0; ks < 2; ++ks) {
      s16x8 pa[2];
#pragma unroll
      for (int m = 0; m < 2; ++m)
        pa[m] = *(const s16x8*)(Pw + (m * 16 + col16) * 144 + ks * 64 +
                                (lane >> 4) * 16);
#pragma unroll
      for (int df = 0; df < 4; ++df) {
        s16x8 vb = *(const s16x8*)(Vt + (df * 16 + col16) * 144 + ks * 64 +
                                   (lane >> 4) * 16);
#pragma unroll
        for (int m = 0; m < 2; ++m)
          Oacc[m][df] = __builtin_amdgcn_mfma_f32_16x16x32_bf16(
              pa[m], vb, Oacc[m][df], 0, 0, 0);
      }
    }
    __syncthreads();  // all waves done with Kt/Vt before next stage
  }

  // normalize + write attn output [sq][h*64+d] bf16
#pragma unroll
  for (int m = 0; m < 2; ++m) {
#pragma unroll
    for (int r = 0; r < 4; ++r) {
      float inv = 1.0f / lrow[m][r];
      int grow = q0 + w * 32 + m * 16 + g4 + r;
#pragma unroll
      for (int df = 0; df < 4; ++df) {
        int gcol = h * 64 + df * 16 + col16;
        aout[(size_t)grow * DM + gcol] = f2bf(Oacc[m][df][r] * inv);
      }
    }
  }
}

extern "C" void kernel_launch(void* const* d_in, const int* in_sizes, int n_in,
                              void* d_out, int out_size, void* d_ws, size_t ws_size,
                              hipStream_t stream) {
  const float* hq = (const float*)d_in[0];
  const float* hkv = (const float*)d_in[1];
  const int* mask = (const int*)d_in[2];
  const float* pbias = (const float*)d_in[3];
  const float* wq = (const float*)d_in[4];
  const float* bq = (const float*)d_in[5];
  const float* wk = (const float*)d_in[6];
  const float* bk = (const float*)d_in[7];
  const float* wv = (const float*)d_in[8];
  const float* bv = (const float*)d_in[9];
  const float* wo = (const float*)d_in[10];
  const float* bo = (const float*)d_in[11];
  float* out = (float*)d_out;
  char* ws = (char*)d_ws;

  const size_t MB = 1024ull * 1024ull;
  unsigned short* cvt = (unsigned short*)ws;             // 6 x 8MB bf16
  unsigned short* Qh = (unsigned short*)(ws + 48 * MB);  // [32][2048][64]
  unsigned short* Kh = (unsigned short*)(ws + 56 * MB);  // [32][2048][64]
  unsigned short* VhT = (unsigned short*)(ws + 64 * MB); // [32][64][2048]
  unsigned short* aout = (unsigned short*)(ws + 72 * MB);// [2048][2048]
  uint32_t* mbits = (uint32_t*)(ws + 80 * MB);           // [2048][64]

  prep_cvt<<<4096, 256, 0, stream>>>(hq, hkv, wq, wk, wv, wo, cvt);
  prep_mask<<<(SQ * SKV) / 256, 256, 0, stream>>>(mask, mbits);
  qkv_gemm<<<dim3(16, 16, 3), 256, 0, stream>>>(cvt, bq, bk, bv, Qh, Kh, VhT);
  attn<<<dim3(SQ / 128, NH), 256, 0, stream>>>(Qh, Kh, VhT, mbits, pbias, aout);
  out_gemm<<<dim3(16, 16), 256, 0, stream>>>(
      aout, cvt + ((size_t)5 << 22), bo, out);
}